// Round 13
// baseline (496.891 us; speedup 1.0000x reference)
//
#include <hip/hip_runtime.h>
#include <hip/hip_bf16.h>

#define NXD   100000
#define AROWS 50000
#define NND   200000   // total nodes
#define EED   2000000  // given edges
#define ETOT  2200000  // + self loops
#define GHD   13
#define MMD   1024

#define OUT_H1 16384
#define OUT_H2 (16384 + AROWS * GHD)

#define NB    196      // buckets for CSR build (1024 nodes each)
#define BSH   10
#define CAP   16000    // staging capacity per bucket (mean 11264)
#define TILE  4096     // edges per bin-pass block (538 blocks)

#define PREP_BIN   538                    // bin blocks (first)
#define PREP_ASM   7422                   // assemble blocks (NXD*19/256)
#define PREP_GRU   392
#define FEAT_BLK   1563                   // (NND/16)/8 half-waves of 16 nodes

typedef __hip_bfloat16 bf16;
typedef unsigned int uvec4 __attribute__((ext_vector_type(4)));

__device__ __forceinline__ float bf2f(bf16 v) { return __bfloat162float(v); }
__device__ __forceinline__ float sigm(float x) { return 1.f / (1.f + __expf(-x)); }
__device__ __forceinline__ float tanhfast(float x) {
    x = fminf(15.f, fmaxf(-15.f, x));
    float t = __expf(-2.f * x);
    return (1.f - t) / (1.f + t);
}
__device__ __forceinline__ float lrelu(float x, float s) { return x > 0.f ? x : s * x; }

__device__ __forceinline__ unsigned short f2bf_bits(float v) {
    bf16 b = __float2bfloat16(v);
    return *reinterpret_cast<unsigned short*>(&b);
}
__device__ __forceinline__ float bflo(unsigned int u) { return __uint_as_float((u & 0xFFFFu) << 16); }
__device__ __forceinline__ float bfhi(unsigned int u) { return __uint_as_float(u & 0xFFFF0000u); }

__device__ __forceinline__ float loadF(const void* p, size_t i, int f32) {
    return f32 ? ((const float*)p)[i] : bf2f(((const bf16*)p)[i]);
}
__device__ __forceinline__ void storeF(void* p, size_t i, float v, int f32) {
    if (f32) ((float*)p)[i] = v;
    else ((bf16*)p)[i] = __float2bfloat16(v);
}

// Inline fp32-detection: wave 0 inspects x's first 128 bf16-slots; result via LDS.
// All threads of the block must reach this (it contains __syncthreads).
__device__ __forceinline__ int flag_from_x(const void* xp, int tid, int* fl) {
    if (tid < 64) {
        const unsigned short* u = (const unsigned short*)xp;
        unsigned short b = u[tid * 2];
        int e = (b >> 7) & 0xFF;
        int viol = (e == 0xFF) || (e < 64) || (e > 190);
        unsigned long long mask = __ballot(viol != 0);
        if (tid == 0) *fl = (__popcll(mask) > 8) ? 1 : 0;
    }
    __syncthreads();
    return *fl;
}

// ---------------- prep: bin (CSR stage) + assemble + both GRUs, one kernel ----------------
__global__ void prep_kernel(const void* __restrict__ x, const void* __restrict__ prefix,
                            const void* __restrict__ msg1, const void* __restrict__ hid1,
                            const void* __restrict__ Wih1, const void* __restrict__ Whh1,
                            const void* __restrict__ bih1, const void* __restrict__ bhh1,
                            const void* __restrict__ msg2, const void* __restrict__ hid2,
                            const void* __restrict__ Wih2, const void* __restrict__ Whh2,
                            const void* __restrict__ bih2, const void* __restrict__ bhh2,
                            void* __restrict__ dout, bf16* __restrict__ bufA,
                            const int* __restrict__ src_e, const int* __restrict__ dst_e,
                            int* __restrict__ gtail, unsigned int* __restrict__ stage) {
    __shared__ int hist[NB];
    __shared__ int base[NB];
    __shared__ int cur[NB];
    __shared__ float WhhL[39 * 13], WihL[39], bihL[39], bhhL[39];
    __shared__ int fl;
    int bid = blockIdx.x, tid = threadIdx.x;
    if (bid < PREP_BIN) {
        // ---- bin ----
        for (int i = tid; i < NB; i += 256) hist[i] = 0;
        __syncthreads();
        int t0 = bid * TILE;
        int tend = t0 + TILE; if (tend > ETOT) tend = ETOT;
        for (int t = t0 + tid; t < tend; t += 256) {
            int d = (t < EED) ? dst_e[t] : (t - EED);
            atomicAdd(&hist[d >> BSH], 1);
        }
        __syncthreads();
        for (int i = tid; i < NB; i += 256) {
            int c = hist[i];
            base[i] = (c > 0) ? atomicAdd(&gtail[i], c) : 0;
            cur[i] = 0;
        }
        __syncthreads();
        for (int t = t0 + tid; t < tend; t += 256) {
            int s, d;
            if (t < EED) { s = src_e[t]; d = dst_e[t]; } else { s = d = t - EED; }
            int b = d >> BSH;
            int p = base[b] + atomicAdd(&cur[b], 1);
            if (p < CAP)
                stage[(size_t)b * CAP + p] = ((unsigned int)(d & 1023) << 18) | (unsigned int)s;
        }
    } else if (bid < PREP_BIN + PREP_ASM) {
        // ---- assemble ----
        int f = flag_from_x(x, tid, &fl);
        int t = (bid - PREP_BIN) * 256 + tid;
        if (t < NXD * 16) {
            bufA[t] = __float2bfloat16(loadF(x, t, f));
        } else {
            int u = t - NXD * 16;
            if (u < NXD * 3) {
                int r = u / 3, c = u - r * 3;
                bufA[(size_t)(NXD + r) * 16 + c] = __float2bfloat16(loadF(prefix, u, f));
            }
        }
    } else {
        // ---- gru2 ----
        int f = flag_from_x(x, tid, &fl);
        int vb = bid - PREP_BIN - PREP_ASM;   // 0..391
        int which = vb >= 196;
        const void* msg = which ? msg2 : msg1;
        const void* hid = which ? hid2 : hid1;
        const void* Wih = which ? Wih2 : Wih1;
        const void* Whh = which ? Whh2 : Whh1;
        const void* bih = which ? bih2 : bih1;
        const void* bhh = which ? bhh2 : bhh1;
        size_t houtbase = which ? (size_t)OUT_H2 : (size_t)OUT_H1;
        int rowbase = which ? AROWS : 0;
        int blk = vb - (which ? 196 : 0);
        for (int i = tid; i < 39 * 13; i += 256) WhhL[i] = loadF(Whh, i, f);
        if (tid < 39) { WihL[tid] = loadF(Wih, tid, f); bihL[tid] = loadF(bih, tid, f); bhhL[tid] = loadF(bhh, tid, f); }
        __syncthreads();
        int n = blk * 256 + tid;
        if (n >= AROWS) return;
        float xv = loadF(msg, n, f);
        float h[GHD];
#pragma unroll
        for (int k = 0; k < GHD; k++) h[k] = loadF(hid, n * GHD + k, f);
#pragma unroll
        for (int k = 0; k < GHD; k++) {
            float gir = fmaf(xv, WihL[k],      bihL[k]);
            float giz = fmaf(xv, WihL[13 + k], bihL[13 + k]);
            float gin = fmaf(xv, WihL[26 + k], bihL[26 + k]);
            float ghr = bhhL[k], ghz = bhhL[13 + k], ghn = bhhL[26 + k];
#pragma unroll
            for (int q = 0; q < GHD; q++) {
                ghr = fmaf(h[q], WhhL[k * 13 + q],        ghr);
                ghz = fmaf(h[q], WhhL[(13 + k) * 13 + q], ghz);
                ghn = fmaf(h[q], WhhL[(26 + k) * 13 + q], ghn);
            }
            float r = sigm(gir + ghr);
            float z = sigm(giz + ghz);
            float nn = tanhfast(gin + r * ghn);
            float o = (1.f - z) * nn + z * h[k];
            storeF(dout, houtbase + (size_t)n * GHD + k, o, f);
            bufA[(size_t)(NXD + rowbase + n) * 16 + 3 + k] = __float2bfloat16(o);
        }
    }
}

// ---------------- feat body (shared by mid_kernel and feat_kernel) ----------------
template <int K>
__device__ __forceinline__ void feat_body(const bf16* __restrict__ xx,
                                          const void* __restrict__ W,
                                          bf16* __restrict__ hbuf, int f,
                                          int vbid, int tid) {
    int j = tid & 31;
    float Wc[K];
#pragma unroll
    for (int k = 0; k < K; k++) Wc[k] = loadF(W, k * 32 + j, f);
    int half = vbid * 8 + (tid >> 5);
    if (half >= NND / 16) return;
    int n0 = half * 16;
#pragma unroll 4
    for (int n = n0; n < n0 + 16; n++) {
        const uvec4* xr4 = (const uvec4*)(xx + (size_t)n * K);
        float v = 0.f;
#pragma unroll
        for (int q = 0; q < K / 8; q++) {
            uvec4 u = xr4[q];
            v = fmaf(bflo(u.x), Wc[q * 8 + 0], v);
            v = fmaf(bfhi(u.x), Wc[q * 8 + 1], v);
            v = fmaf(bflo(u.y), Wc[q * 8 + 2], v);
            v = fmaf(bfhi(u.y), Wc[q * 8 + 3], v);
            v = fmaf(bflo(u.z), Wc[q * 8 + 4], v);
            v = fmaf(bfhi(u.z), Wc[q * 8 + 5], v);
            v = fmaf(bflo(u.w), Wc[q * 8 + 6], v);
            v = fmaf(bfhi(u.w), Wc[q * 8 + 7], v);
        }
        hbuf[(size_t)n * 32 + j] = __float2bfloat16(v);
    }
}

// ---------------- mid: build (CSR place + degree-sorted order) + feat1 ----------------
// NOTE: stage is a DEDICATED buffer (not aliased with hbuf) — build blocks read
// stage while feat1 blocks write hbuf concurrently.
__global__ void mid_kernel(const unsigned int* __restrict__ stage, const int* __restrict__ gtail,
                           int* __restrict__ offs, int* __restrict__ csr, int* __restrict__ order,
                           const bf16* __restrict__ xx, const void* __restrict__ W,
                           bf16* __restrict__ hbuf, const void* __restrict__ x) {
    __shared__ int cnt[1024];
    __shared__ int loc[1024];
    __shared__ int cur[1024];
    __shared__ int lds[256];
    __shared__ int dh[64];
    __shared__ int fl;
    int bid = blockIdx.x, tid = threadIdx.x;
    if (bid >= NB) {
        // ---- feat1 (K=16) ----
        int f = flag_from_x(x, tid, &fl);
        feat_body<16>(xx, W, hbuf, f, bid - NB, tid);
        return;
    }
    // ---- build ----
    int b = bid;
    int v = (tid < NB) ? gtail[tid] : 0;
    lds[tid] = v; __syncthreads();
    for (int off = 1; off < 256; off <<= 1) {
        int t2 = (tid >= off) ? lds[tid - off] : 0;
        __syncthreads();
        lds[tid] += t2;
        __syncthreads();
    }
    __shared__ int ebs;
    if (tid == b) ebs = lds[tid] - v;
    __syncthreads();
    int eb = ebs;
    int nE = gtail[b]; if (nE > CAP) nE = CAP;
    const unsigned int* st = stage + (size_t)b * CAP;
    for (int i = tid; i < 1024; i += 256) cnt[i] = 0;
    __syncthreads();
    for (int i = tid; i < nE; i += 256)
        atomicAdd(&cnt[st[i] >> 18], 1);
    __syncthreads();
    int c0 = cnt[tid * 4], c1 = cnt[tid * 4 + 1], c2 = cnt[tid * 4 + 2], c3 = cnt[tid * 4 + 3];
    int s = c0 + c1 + c2 + c3;
    lds[tid] = s; __syncthreads();
    for (int off = 1; off < 256; off <<= 1) {
        int t2 = (tid >= off) ? lds[tid - off] : 0;
        __syncthreads();
        lds[tid] += t2;
        __syncthreads();
    }
    int run = lds[tid] - s;
    loc[tid * 4]     = run;
    loc[tid * 4 + 1] = run + c0;
    loc[tid * 4 + 2] = run + c0 + c1;
    loc[tid * 4 + 3] = run + c0 + c1 + c2;
    __syncthreads();
    int nodebase = b << BSH;
    int bcnt = NND - nodebase; if (bcnt > 1024) bcnt = 1024;
    for (int i = tid; i < 1024; i += 256) {
        cur[i] = loc[i];
        int n = nodebase + i;
        if (n < NND) offs[n] = eb + loc[i];
    }
    if (b == 0 && tid == 0) offs[NND] = ETOT;
    if (tid < 64) dh[tid] = 0;
    __syncthreads();
    for (int i = tid; i < nE; i += 256) {
        unsigned int e = st[i];
        int dl = e >> 18;
        int src = e & 0x3FFFF;
        int p = atomicAdd(&cur[dl], 1);
        csr[eb + p] = src;
    }
    // ---- degree-sorted node order (counting sort over degree, cap 63) ----
    for (int i = tid; i < bcnt; i += 256) {
        int dcl = cnt[i]; if (dcl > 63) dcl = 63;
        atomicAdd(&dh[dcl], 1);
    }
    __syncthreads();
    if (tid == 0) {
        int acc = 0;
        for (int k = 0; k < 64; k++) { int c = dh[k]; dh[k] = acc; acc += c; }
    }
    __syncthreads();
    for (int i = tid; i < bcnt; i += 256) {
        int dcl = cnt[i]; if (dcl > 63) dcl = 63;
        int pos = atomicAdd(&dh[dcl], 1);
        order[nodebase + pos] = nodebase + i;
    }
}

// ---------------- standalone feat (layers 2,3) ----------------
template <int K>
__global__ void feat_kernel(const bf16* __restrict__ xx, const void* __restrict__ W,
                            bf16* __restrict__ hbuf, const void* __restrict__ x) {
    __shared__ int fl;
    int tid = threadIdx.x;
    int f = flag_from_x(x, tid, &fl);
    feat_body<K>(xx, W, hbuf, f, blockIdx.x, tid);
}

// ---------------- aggregation: degree-ordered nodes, depth-3 pipeline ----------------
__global__ void agg_kernel(const bf16* __restrict__ hbuf, const int* __restrict__ offs,
                           const int* __restrict__ csr, const int* __restrict__ order,
                           const void* __restrict__ asrc, const void* __restrict__ adst,
                           const void* __restrict__ bias, bf16* __restrict__ xxout,
                           const void* __restrict__ x) {
    __shared__ float bl[32], asl[32], adl[32];
    __shared__ int fl;
    int tid = threadIdx.x;
    int f = flag_from_x(x, tid, &fl);
    if (tid < 32) {
        bl[tid]  = loadF(bias, tid, f);
        asl[tid] = loadF(asrc, tid, f);
        adl[tid] = loadF(adst, tid, f);
    }
    __syncthreads();
    int n = order[blockIdx.x * 64 + (tid >> 2)];
    int j = tid & 3;                 // head j, channels 8j..8j+7
    int cb = 8 * j;
    float A0 = asl[cb], A1 = asl[cb + 1], A2 = asl[cb + 2], A3 = asl[cb + 3];
    float A4 = asl[cb + 4], A5 = asl[cb + 5], A6 = asl[cb + 6], A7 = asl[cb + 7];
    uvec4 hd = *(const uvec4*)(hbuf + (size_t)n * 32 + cb);
    float adv = bflo(hd.x) * adl[cb]     + bfhi(hd.x) * adl[cb + 1]
              + bflo(hd.y) * adl[cb + 2] + bfhi(hd.y) * adl[cb + 3]
              + bflo(hd.z) * adl[cb + 4] + bfhi(hd.z) * adl[cb + 5]
              + bflo(hd.w) * adl[cb + 6] + bfhi(hd.w) * adl[cb + 7];
    int beg = offs[n], end = offs[n + 1];
    int cnt = end - beg;
    const int* cp = csr + beg;
    // depth-3 preamble (self-loop guarantees cnt >= 1)
    uvec4 h0 = *(const uvec4*)(hbuf + (size_t)cp[0] * 32 + cb);
    uvec4 h1 = h0, h2 = h0;
    if (cnt > 1) h1 = *(const uvec4*)(hbuf + (size_t)cp[1] * 32 + cb);
    if (cnt > 2) h2 = *(const uvec4*)(hbuf + (size_t)cp[2] * 32 + cb);
    float den = 0.f;
    float a0 = 0.f, a1 = 0.f, a2 = 0.f, a3 = 0.f, a4 = 0.f, a5 = 0.f, a6 = 0.f, a7 = 0.f;
    for (int i = 0; i < cnt; i++) {
        uvec4 hn = (uvec4)(0u);
        if (i + 3 < cnt) {
            int sn = cp[i + 3];
            hn = *(const uvec4*)(hbuf + (size_t)sn * 32 + cb);
        }
        float v0 = bflo(h0.x), v1 = bfhi(h0.x), v2 = bflo(h0.y), v3 = bfhi(h0.y);
        float v4 = bflo(h0.z), v5 = bfhi(h0.z), v6 = bflo(h0.w), v7 = bfhi(h0.w);
        float as = v0 * A0 + v1 * A1 + v2 * A2 + v3 * A3
                 + v4 * A4 + v5 * A5 + v6 * A6 + v7 * A7;
        float e = as + adv;
        e = e > 0.f ? e : 0.2f * e;
        e = fminf(50.f, fmaxf(-50.f, e));
        float w = __expf(e);
        den += w;
        a0 = fmaf(w, v0, a0); a1 = fmaf(w, v1, a1);
        a2 = fmaf(w, v2, a2); a3 = fmaf(w, v3, a3);
        a4 = fmaf(w, v4, a4); a5 = fmaf(w, v5, a5);
        a6 = fmaf(w, v6, a6); a7 = fmaf(w, v7, a7);
        h0 = h1; h1 = h2; h2 = hn;
    }
    float inv = 1.f / den;
    float o0 = lrelu(fmaf(a0, inv, bl[cb + 0]), 0.01f);
    float o1 = lrelu(fmaf(a1, inv, bl[cb + 1]), 0.01f);
    float o2 = lrelu(fmaf(a2, inv, bl[cb + 2]), 0.01f);
    float o3 = lrelu(fmaf(a3, inv, bl[cb + 3]), 0.01f);
    float o4 = lrelu(fmaf(a4, inv, bl[cb + 4]), 0.01f);
    float o5 = lrelu(fmaf(a5, inv, bl[cb + 5]), 0.01f);
    float o6 = lrelu(fmaf(a6, inv, bl[cb + 6]), 0.01f);
    float o7 = lrelu(fmaf(a7, inv, bl[cb + 7]), 0.01f);
    uvec4 p;
    p.x = ((unsigned int)f2bf_bits(o1) << 16) | f2bf_bits(o0);
    p.y = ((unsigned int)f2bf_bits(o3) << 16) | f2bf_bits(o2);
    p.z = ((unsigned int)f2bf_bits(o5) << 16) | f2bf_bits(o4);
    p.w = ((unsigned int)f2bf_bits(o7) << 16) | f2bf_bits(o6);
    __builtin_nontemporal_store(p, (uvec4*)(xxout + (size_t)n * 32 + cb));
}

// ---------------- layer 4: edge-parallel, one block per function node ----------------
__global__ void layer4_kernel(const bf16* __restrict__ xx,
                              const void* __restrict__ W4,
                              const void* __restrict__ asrc,
                              const void* __restrict__ adst,
                              const void* __restrict__ b4,
                              const int* __restrict__ fidx, const int* __restrict__ offs,
                              const int* __restrict__ csr, float* __restrict__ pool,
                              const void* __restrict__ x) {
    __shared__ float Wl[32 * 128];
    __shared__ float asl[128], adl[128], bl[32];
    __shared__ float accs[4][32];
    __shared__ float dens[4];
    __shared__ int fl;
    int tid = threadIdx.x;
    int f = flag_from_x(x, tid, &fl);
    for (int i = tid; i < 32 * 128; i += 256) Wl[i] = loadF(W4, i, f);
    if (tid < 128) { asl[tid] = loadF(asrc, tid, f); adl[tid] = loadF(adst, tid, f); accs[tid >> 5][tid & 31] = 0.f; }
    if (tid < 32) bl[tid] = loadF(b4, tid, f);
    if (tid < 4) dens[tid] = 0.f;
    __syncthreads();
    int g = blockIdx.x;
    int d = fidx[g];
    int wave = tid >> 6, lane = tid & 63;
    int c = lane & 31;
    int h0 = lane >> 5;
    int h1 = h0 + 2;
    const uvec4* xd4 = (const uvec4*)(xx + (size_t)d * 32);
    uvec4 du0 = xd4[0], du1 = xd4[1];
    float v0 = 0.f, v1 = 0.f;
    {
        unsigned int us[8] = {du0.x, du0.y, du0.z, du0.w, du1.x, du1.y, du1.z, du1.w};
#pragma unroll
        for (int q = 0; q < 8; q++) {
            unsigned int u = us[q];
            int k = 2 * q;
            v0 = fmaf(bflo(u), Wl[k * 128 + lane], v0);       v0 = fmaf(bfhi(u), Wl[(k + 1) * 128 + lane], v0);
            v1 = fmaf(bflo(u), Wl[k * 128 + lane + 64], v1);  v1 = fmaf(bfhi(u), Wl[(k + 1) * 128 + lane + 64], v1);
        }
    }
    float ad0 = v0 * adl[h0 * 32 + c];
    float ad1 = v1 * adl[h1 * 32 + c];
#pragma unroll
    for (int mk = 1; mk < 32; mk <<= 1) { ad0 += __shfl_xor(ad0, mk); ad1 += __shfl_xor(ad1, mk); }
    int beg = offs[d], end = offs[d + 1];
    float den0 = 0.f, den1 = 0.f, acc0 = 0.f, acc1 = 0.f;
    for (int i = beg + wave; i < end; i += 4) {
        int s = csr[i];
        const uvec4* xs4 = (const uvec4*)(xx + (size_t)s * 32);
        uvec4 su0 = xs4[0], su1 = xs4[1];
        float s0 = 0.f, s1 = 0.f;
        unsigned int us[8] = {su0.x, su0.y, su0.z, su0.w, su1.x, su1.y, su1.z, su1.w};
#pragma unroll
        for (int q = 0; q < 8; q++) {
            unsigned int u = us[q];
            int k = 2 * q;
            s0 = fmaf(bflo(u), Wl[k * 128 + lane], s0);       s0 = fmaf(bfhi(u), Wl[(k + 1) * 128 + lane], s0);
            s1 = fmaf(bflo(u), Wl[k * 128 + lane + 64], s1);  s1 = fmaf(bfhi(u), Wl[(k + 1) * 128 + lane + 64], s1);
        }
        float as0 = s0 * asl[h0 * 32 + c];
        float as1 = s1 * asl[h1 * 32 + c];
#pragma unroll
        for (int mk = 1; mk < 32; mk <<= 1) { as0 += __shfl_xor(as0, mk); as1 += __shfl_xor(as1, mk); }
        float e0 = lrelu(as0 + ad0, 0.2f);
        float e1 = lrelu(as1 + ad1, 0.2f);
        e0 = fminf(50.f, fmaxf(-50.f, e0));
        e1 = fminf(50.f, fmaxf(-50.f, e1));
        float w0 = __expf(e0), w1 = __expf(e1);
        den0 += w0; acc0 = fmaf(w0, s0, acc0);
        den1 += w1; acc1 = fmaf(w1, s1, acc1);
    }
    atomicAdd(&accs[h0][c], acc0);
    atomicAdd(&accs[h1][c], acc1);
    if (c == 0) { atomicAdd(&dens[h0], den0); atomicAdd(&dens[h1], den1); }
    __syncthreads();
    if (tid < 32) {
        float t = accs[0][tid] / dens[0] + accs[1][tid] / dens[1]
                + accs[2][tid] / dens[2] + accs[3][tid] / dens[3];
        float o = t * 0.25f + bl[tid];
        pool[g * 32 + tid] = lrelu(o, 0.01f);
    }
}

// ---------------- fused final scoring ----------------
__global__ void tail_kernel(const void* __restrict__ Wq, const void* __restrict__ Wk,
                            const void* __restrict__ Ws, const void* __restrict__ bs,
                            const int* __restrict__ gidx, const int* __restrict__ gsrc,
                            const float* __restrict__ pool, void* __restrict__ out,
                            const void* __restrict__ x) {
    __shared__ float vq[128], vk[128];
    __shared__ float sq[4096], sk[4096];
    __shared__ int fl;
    int tid = threadIdx.x;  // 256
    int f = flag_from_x(x, tid, &fl);
    {
        int which = tid >> 7;
        int i = tid & 127;
        int h = i >> 5, dd = i & 31;
        const void* Wm = which ? Wk : Wq;
        float sum = 0.f;
#pragma unroll
        for (int o = 0; o < 32; o++)
            sum = fmaf(loadF(Wm, (h * 32 + dd) * 32 + o, f), loadF(Ws, h * 64 + which * 32 + o, f), sum);
        (which ? vk : vq)[i] = sum;
    }
    __syncthreads();
    for (int idx = tid; idx < 8192; idx += 256) {
        int which = idx >> 12;
        int i = idx & 4095;
        int g = i >> 2, h = i & 3;
        const float* V = which ? vk : vq;
        float s = 0.f;
#pragma unroll
        for (int dd = 0; dd < 32; dd++) s = fmaf(pool[g * 32 + dd], V[h * 32 + dd], s);
        (which ? sk : sq)[i] = s;
    }
    __syncthreads();
    for (int t = tid; t < 4096; t += 256) {
        int g = t >> 2, h = t & 3;
        int i = gidx[g];
        float bsv = loadF(bs, h, f);
        float sqi = sq[i * 4 + h];
        float trg = sigm(sqi + sk[i * 4 + h] + bsv);
        float ga[3];
#pragma unroll
        for (int q = 0; q < 3; q++) {
            int jj = gsrc[g * 4 + 1 + q];
            ga[q] = sigm(sqi + sk[jj * 4 + h] + bsv);
        }
        float ss = (ga[0] + ga[1] + ga[2]) * (1.f / 3.f);
        float mx = fmaxf(ss, trg);
        float e0 = __expf(ss - mx), e1 = __expf(trg - mx);
        float inv = 1.f / (e0 + e1);
        float tw0 = e0 * inv, tw1 = e1 * inv;
        float mg = fmaxf(ga[0], fmaxf(ga[1], ga[2]));
        float w0 = __expf(ga[0] - mg), w1 = __expf(ga[1] - mg), w2 = __expf(ga[2] - mg);
        float wi = tw0 * 3.f / (w0 + w1 + w2);
        storeF(out, g * 16 + 0 + h,  tw1,     f);
        storeF(out, g * 16 + 4 + h,  w0 * wi, f);
        storeF(out, g * 16 + 8 + h,  w1 * wi, f);
        storeF(out, g * 16 + 12 + h, w2 * wi, f);
    }
}

extern "C" void kernel_launch(void* const* d_in, const int* in_sizes, int n_in,
                              void* d_out, int out_size, void* d_ws, size_t ws_size,
                              hipStream_t stream) {
    // -------- inputs --------
    const void* x        = d_in[0];
    const int*  ei       = (const int*)d_in[1];
    const void* a2s_msg  = d_in[2];
    const void* a2s_hid  = d_in[3];
    const void* s2a_msg  = d_in[4];
    const void* s2a_hid  = d_in[5];
    const void* prefix   = d_in[6];
    const int*  fidx     = (const int*)d_in[7];
    const int*  gidx     = (const int*)d_in[8];
    const int*  gsrc     = (const int*)d_in[9];
    const void* g1_Wih   = d_in[10];
    const void* g1_Whh   = d_in[11];
    const void* g1_bih   = d_in[12];
    const void* g1_bhh   = d_in[13];
    const void* g2_Wih   = d_in[14];
    const void* g2_Whh   = d_in[15];
    const void* g2_bih   = d_in[16];
    const void* g2_bhh   = d_in[17];
    const void* W1  = d_in[18];
    const void* as1 = d_in[19];
    const void* ad1 = d_in[20];
    const void* b1  = d_in[21];
    const void* W2  = d_in[22];
    const void* as2 = d_in[23];
    const void* ad2 = d_in[24];
    const void* b2  = d_in[25];
    const void* W3  = d_in[26];
    const void* as3 = d_in[27];
    const void* ad3 = d_in[28];
    const void* b3  = d_in[29];
    const void* W4  = d_in[30];
    const void* as4 = d_in[31];
    const void* ad4 = d_in[32];
    const void* b4  = d_in[33];
    const void* Wq  = d_in[34];
    const void* Wk  = d_in[35];
    const void* Ws  = d_in[36];
    const void* bs  = d_in[37];

    const int* src_e = ei;
    const int* dst_e = ei + EED;

    // -------- workspace layout (~50 MB of 256 MB) --------
    char* wp = (char*)d_ws;
    auto alloc = [&](size_t bytes) {
        char* p = wp;
        wp += (bytes + 255) & ~(size_t)255;
        return p;
    };
    int*   csr   = (int*)alloc((size_t)ETOT * 4);              // 8.8 MB
    int*   offs  = (int*)alloc((size_t)(NND + 1) * 4);         // 0.8 MB
    int*   order = (int*)alloc((size_t)NND * 4);               // 0.8 MB
    int*   gtail = (int*)alloc((size_t)NB * 4);
    float* pool  = (float*)alloc((size_t)MMD * 32 * 4);
    bf16*  bufA  = (bf16*)alloc((size_t)NND * 32 * 2);         // 12.8 MB
    bf16*  bufB  = (bf16*)alloc((size_t)NND * 32 * 2);         // 12.8 MB
    unsigned int* stage = (unsigned int*)alloc((size_t)NB * CAP * 4);  // 12.25 MB, DEDICATED

    // -------- prep: bin + assemble + gru2 (one kernel) --------
    hipMemsetAsync(gtail, 0, (size_t)NB * 4, stream);
    prep_kernel<<<PREP_BIN + PREP_ASM + PREP_GRU, 256, 0, stream>>>(
        x, prefix,
        a2s_msg, a2s_hid, g1_Wih, g1_Whh, g1_bih, g1_bhh,
        s2a_msg, s2a_hid, g2_Wih, g2_Whh, g2_bih, g2_bhh,
        d_out, bufA, src_e, dst_e, gtail, stage);

    // -------- mid: build (+degree order) + feat1 --------
    mid_kernel<<<NB + FEAT_BLK, 256, 0, stream>>>(stage, gtail, offs, csr, order,
                                                  bufA, W1, bufB, x);

    // -------- GAT layers --------
    const int nblk_agg = NND / 64;  // 3125
    agg_kernel<<<nblk_agg, 256, 0, stream>>>(bufB, offs, csr, order, as1, ad1, b1, bufA, x);
    feat_kernel<32><<<FEAT_BLK, 256, 0, stream>>>(bufA, W2, bufB, x);
    agg_kernel<<<nblk_agg, 256, 0, stream>>>(bufB, offs, csr, order, as2, ad2, b2, bufA, x);
    feat_kernel<32><<<FEAT_BLK, 256, 0, stream>>>(bufA, W3, bufB, x);
    agg_kernel<<<nblk_agg, 256, 0, stream>>>(bufB, offs, csr, order, as3, ad3, b3, bufA, x);

    // -------- layer 4 + tail --------
    layer4_kernel<<<MMD, 256, 0, stream>>>(bufA, W4, as4, ad4, b4, fidx, offs, csr, pool, x);
    tail_kernel<<<1, 256, 0, stream>>>(Wq, Wk, Ws, bs, gidx, gsrc, pool, d_out, x);
}

// Round 14
// 446.228 us; speedup vs baseline: 1.1135x; 1.1135x over previous
//
#include <hip/hip_runtime.h>
#include <hip/hip_bf16.h>

#define NXD   100000
#define AROWS 50000
#define NND   200000   // total nodes
#define EED   2000000  // given edges
#define ETOT  2200000  // + self loops
#define GHD   13
#define MMD   1024

#define OUT_H1 16384
#define OUT_H2 (16384 + AROWS * GHD)

#define NB    196      // buckets for CSR build (1024 nodes each)
#define BSH   10
#define CAP   16000    // staging capacity per bucket (mean 11264)
#define TILE  4096     // edges per bin-pass block (538 blocks)

#define ASM_BLK    7422                   // assemble blocks (NXD*19/256)
#define GRU_BLK    392
#define FEAT_BLK   1563                   // (NND/16)/8 half-waves of 16 nodes

typedef __hip_bfloat16 bf16;
typedef unsigned int uvec4 __attribute__((ext_vector_type(4)));

__device__ __forceinline__ float bf2f(bf16 v) { return __bfloat162float(v); }
__device__ __forceinline__ float sigm(float x) { return 1.f / (1.f + __expf(-x)); }
__device__ __forceinline__ float tanhfast(float x) {
    x = fminf(15.f, fmaxf(-15.f, x));
    float t = __expf(-2.f * x);
    return (1.f - t) / (1.f + t);
}
__device__ __forceinline__ float lrelu(float x, float s) { return x > 0.f ? x : s * x; }

__device__ __forceinline__ unsigned short f2bf_bits(float v) {
    bf16 b = __float2bfloat16(v);
    return *reinterpret_cast<unsigned short*>(&b);
}
__device__ __forceinline__ float bflo(unsigned int u) { return __uint_as_float((u & 0xFFFFu) << 16); }
__device__ __forceinline__ float bfhi(unsigned int u) { return __uint_as_float(u & 0xFFFF0000u); }

__device__ __forceinline__ float loadF(const void* p, size_t i, int f32) {
    return f32 ? ((const float*)p)[i] : bf2f(((const bf16*)p)[i]);
}
__device__ __forceinline__ void storeF(void* p, size_t i, float v, int f32) {
    if (f32) ((float*)p)[i] = v;
    else ((bf16*)p)[i] = __float2bfloat16(v);
}

// Inline fp32-detection: wave 0 inspects x's first 128 bf16-slots; result via LDS.
// All threads of the block must reach this (contains __syncthreads).
__device__ __forceinline__ int flag_from_x(const void* xp, int tid, int* fl) {
    if (tid < 64) {
        const unsigned short* u = (const unsigned short*)xp;
        unsigned short b = u[tid * 2];
        int e = (b >> 7) & 0xFF;
        int viol = (e == 0xFF) || (e < 64) || (e > 190);
        unsigned long long mask = __ballot(viol != 0);
        if (tid == 0) *fl = (__popcll(mask) > 8) ? 1 : 0;
    }
    __syncthreads();
    return *fl;
}

// ---------------- CSR bin pass (separate: slow branch, keep off the critical fusion) ----------------
__global__ void bin_kernel(const int* __restrict__ src_e, const int* __restrict__ dst_e,
                           int* __restrict__ gtail, unsigned int* __restrict__ stage) {
    __shared__ int hist[NB];
    __shared__ int base[NB];
    __shared__ int cur[NB];
    int tid = threadIdx.x;
    for (int i = tid; i < NB; i += 256) hist[i] = 0;
    __syncthreads();
    int t0 = blockIdx.x * TILE;
    int tend = t0 + TILE; if (tend > ETOT) tend = ETOT;
    for (int t = t0 + tid; t < tend; t += 256) {
        int d = (t < EED) ? dst_e[t] : (t - EED);
        atomicAdd(&hist[d >> BSH], 1);
    }
    __syncthreads();
    for (int i = tid; i < NB; i += 256) {
        int c = hist[i];
        base[i] = (c > 0) ? atomicAdd(&gtail[i], c) : 0;
        cur[i] = 0;
    }
    __syncthreads();
    for (int t = t0 + tid; t < tend; t += 256) {
        int s, d;
        if (t < EED) { s = src_e[t]; d = dst_e[t]; } else { s = d = t - EED; }
        int b = d >> BSH;
        int p = base[b] + atomicAdd(&cur[b], 1);
        if (p < CAP)
            stage[(size_t)b * CAP + p] = ((unsigned int)(d & 1023) << 18) | (unsigned int)s;
    }
}

// ---------------- assemble + both GRUs (fused; both trivially parallel) ----------------
__global__ void asmgru_kernel(const void* __restrict__ x, const void* __restrict__ prefix,
                              const void* __restrict__ msg1, const void* __restrict__ hid1,
                              const void* __restrict__ Wih1, const void* __restrict__ Whh1,
                              const void* __restrict__ bih1, const void* __restrict__ bhh1,
                              const void* __restrict__ msg2, const void* __restrict__ hid2,
                              const void* __restrict__ Wih2, const void* __restrict__ Whh2,
                              const void* __restrict__ bih2, const void* __restrict__ bhh2,
                              void* __restrict__ dout, bf16* __restrict__ bufA) {
    __shared__ float WhhL[39 * 13], WihL[39], bihL[39], bhhL[39];
    __shared__ int fl;
    int bid = blockIdx.x, tid = threadIdx.x;
    int f = flag_from_x(x, tid, &fl);
    if (bid < ASM_BLK) {
        int t = bid * 256 + tid;
        if (t < NXD * 16) {
            bufA[t] = __float2bfloat16(loadF(x, t, f));
        } else {
            int u = t - NXD * 16;
            if (u < NXD * 3) {
                int r = u / 3, c = u - r * 3;
                bufA[(size_t)(NXD + r) * 16 + c] = __float2bfloat16(loadF(prefix, u, f));
            }
        }
        return;
    }
    int vb = bid - ASM_BLK;   // 0..391
    int which = vb >= 196;
    const void* msg = which ? msg2 : msg1;
    const void* hid = which ? hid2 : hid1;
    const void* Wih = which ? Wih2 : Wih1;
    const void* Whh = which ? Whh2 : Whh1;
    const void* bih = which ? bih2 : bih1;
    const void* bhh = which ? bhh2 : bhh1;
    size_t houtbase = which ? (size_t)OUT_H2 : (size_t)OUT_H1;
    int rowbase = which ? AROWS : 0;
    int blk = vb - (which ? 196 : 0);
    for (int i = tid; i < 39 * 13; i += 256) WhhL[i] = loadF(Whh, i, f);
    if (tid < 39) { WihL[tid] = loadF(Wih, tid, f); bihL[tid] = loadF(bih, tid, f); bhhL[tid] = loadF(bhh, tid, f); }
    __syncthreads();
    int n = blk * 256 + tid;
    if (n >= AROWS) return;
    float xv = loadF(msg, n, f);
    float h[GHD];
#pragma unroll
    for (int k = 0; k < GHD; k++) h[k] = loadF(hid, n * GHD + k, f);
#pragma unroll
    for (int k = 0; k < GHD; k++) {
        float gir = fmaf(xv, WihL[k],      bihL[k]);
        float giz = fmaf(xv, WihL[13 + k], bihL[13 + k]);
        float gin = fmaf(xv, WihL[26 + k], bihL[26 + k]);
        float ghr = bhhL[k], ghz = bhhL[13 + k], ghn = bhhL[26 + k];
#pragma unroll
        for (int q = 0; q < GHD; q++) {
            ghr = fmaf(h[q], WhhL[k * 13 + q],        ghr);
            ghz = fmaf(h[q], WhhL[(13 + k) * 13 + q], ghz);
            ghn = fmaf(h[q], WhhL[(26 + k) * 13 + q], ghn);
        }
        float r = sigm(gir + ghr);
        float z = sigm(giz + ghz);
        float nn = tanhfast(gin + r * ghn);
        float o = (1.f - z) * nn + z * h[k];
        storeF(dout, houtbase + (size_t)n * GHD + k, o, f);
        bufA[(size_t)(NXD + rowbase + n) * 16 + 3 + k] = __float2bfloat16(o);
    }
}

// ---------------- feat body ----------------
template <int K>
__device__ __forceinline__ void feat_body(const bf16* __restrict__ xx,
                                          const void* __restrict__ W,
                                          bf16* __restrict__ hbuf, int f,
                                          int vbid, int tid) {
    int j = tid & 31;
    float Wc[K];
#pragma unroll
    for (int k = 0; k < K; k++) Wc[k] = loadF(W, k * 32 + j, f);
    int half = vbid * 8 + (tid >> 5);
    if (half >= NND / 16) return;
    int n0 = half * 16;
#pragma unroll 4
    for (int n = n0; n < n0 + 16; n++) {
        const uvec4* xr4 = (const uvec4*)(xx + (size_t)n * K);
        float v = 0.f;
#pragma unroll
        for (int q = 0; q < K / 8; q++) {
            uvec4 u = xr4[q];
            v = fmaf(bflo(u.x), Wc[q * 8 + 0], v);
            v = fmaf(bfhi(u.x), Wc[q * 8 + 1], v);
            v = fmaf(bflo(u.y), Wc[q * 8 + 2], v);
            v = fmaf(bfhi(u.y), Wc[q * 8 + 3], v);
            v = fmaf(bflo(u.z), Wc[q * 8 + 4], v);
            v = fmaf(bfhi(u.z), Wc[q * 8 + 5], v);
            v = fmaf(bflo(u.w), Wc[q * 8 + 6], v);
            v = fmaf(bfhi(u.w), Wc[q * 8 + 7], v);
        }
        hbuf[(size_t)n * 32 + j] = __float2bfloat16(v);
    }
}

// ---------------- mid: CSR build + feat1 (stage is DEDICATED, no aliasing) ----------------
__global__ void mid_kernel(const unsigned int* __restrict__ stage, const int* __restrict__ gtail,
                           int* __restrict__ offs, int* __restrict__ csr,
                           const bf16* __restrict__ xx, const void* __restrict__ W,
                           bf16* __restrict__ hbuf, const void* __restrict__ x) {
    __shared__ int cnt[1024];
    __shared__ int loc[1024];
    __shared__ int cur[1024];
    __shared__ int lds[256];
    __shared__ int fl;
    int bid = blockIdx.x, tid = threadIdx.x;
    if (bid >= NB) {
        int f = flag_from_x(x, tid, &fl);
        feat_body<16>(xx, W, hbuf, f, bid - NB, tid);
        return;
    }
    int b = bid;
    int v = (tid < NB) ? gtail[tid] : 0;
    lds[tid] = v; __syncthreads();
    for (int off = 1; off < 256; off <<= 1) {
        int t2 = (tid >= off) ? lds[tid - off] : 0;
        __syncthreads();
        lds[tid] += t2;
        __syncthreads();
    }
    __shared__ int ebs;
    if (tid == b) ebs = lds[tid] - v;
    __syncthreads();
    int eb = ebs;
    int nE = gtail[b]; if (nE > CAP) nE = CAP;
    const unsigned int* st = stage + (size_t)b * CAP;
    for (int i = tid; i < 1024; i += 256) cnt[i] = 0;
    __syncthreads();
    for (int i = tid; i < nE; i += 256)
        atomicAdd(&cnt[st[i] >> 18], 1);
    __syncthreads();
    int c0 = cnt[tid * 4], c1 = cnt[tid * 4 + 1], c2 = cnt[tid * 4 + 2], c3 = cnt[tid * 4 + 3];
    int s = c0 + c1 + c2 + c3;
    lds[tid] = s; __syncthreads();
    for (int off = 1; off < 256; off <<= 1) {
        int t2 = (tid >= off) ? lds[tid - off] : 0;
        __syncthreads();
        lds[tid] += t2;
        __syncthreads();
    }
    int run = lds[tid] - s;
    loc[tid * 4]     = run;
    loc[tid * 4 + 1] = run + c0;
    loc[tid * 4 + 2] = run + c0 + c1;
    loc[tid * 4 + 3] = run + c0 + c1 + c2;
    __syncthreads();
    int nodebase = b << BSH;
    for (int i = tid; i < 1024; i += 256) {
        cur[i] = loc[i];
        int n = nodebase + i;
        if (n < NND) offs[n] = eb + loc[i];
    }
    if (b == 0 && tid == 0) offs[NND] = ETOT;
    __syncthreads();
    for (int i = tid; i < nE; i += 256) {
        unsigned int e = st[i];
        int dl = e >> 18;
        int src = e & 0x3FFFF;
        int p = atomicAdd(&cur[dl], 1);
        csr[eb + p] = src;
    }
}

// ---------------- standalone feat (layers 2,3) ----------------
template <int K>
__global__ void feat_kernel(const bf16* __restrict__ xx, const void* __restrict__ W,
                            bf16* __restrict__ hbuf, const void* __restrict__ x) {
    __shared__ int fl;
    int tid = threadIdx.x;
    int f = flag_from_x(x, tid, &fl);
    feat_body<K>(xx, W, hbuf, f, blockIdx.x, tid);
}

// ---------------- aggregation: r11 form (identity order, depth-2, low VGPR) ----------------
__global__ void __launch_bounds__(256, 8)
agg_kernel(const bf16* __restrict__ hbuf, const int* __restrict__ offs,
           const int* __restrict__ csr, const void* __restrict__ asrc,
           const void* __restrict__ adst, const void* __restrict__ bias,
           bf16* __restrict__ xxout, const void* __restrict__ x) {
    __shared__ float bl[32], asl[32], adl[32];
    __shared__ int fl;
    int tid = threadIdx.x;
    int f = flag_from_x(x, tid, &fl);
    if (tid < 32) {
        bl[tid]  = loadF(bias, tid, f);
        asl[tid] = loadF(asrc, tid, f);
        adl[tid] = loadF(adst, tid, f);
    }
    __syncthreads();
    int n = blockIdx.x * 64 + (tid >> 2);
    int j = tid & 3;                 // head j, channels 8j..8j+7
    int cb = 8 * j;
    float A0 = asl[cb], A1 = asl[cb + 1], A2 = asl[cb + 2], A3 = asl[cb + 3];
    float A4 = asl[cb + 4], A5 = asl[cb + 5], A6 = asl[cb + 6], A7 = asl[cb + 7];
    uvec4 hd = *(const uvec4*)(hbuf + (size_t)n * 32 + cb);
    float adv = bflo(hd.x) * adl[cb]     + bfhi(hd.x) * adl[cb + 1]
              + bflo(hd.y) * adl[cb + 2] + bfhi(hd.y) * adl[cb + 3]
              + bflo(hd.z) * adl[cb + 4] + bfhi(hd.z) * adl[cb + 5]
              + bflo(hd.w) * adl[cb + 6] + bfhi(hd.w) * adl[cb + 7];
    int beg = offs[n], end = offs[n + 1];
    int cnt = end - beg;
    const int* cp = csr + beg;
    uvec4 h0 = *(const uvec4*)(hbuf + (size_t)cp[0] * 32 + cb);
    uvec4 h1 = h0;
    if (cnt > 1) h1 = *(const uvec4*)(hbuf + (size_t)cp[1] * 32 + cb);
    float den = 0.f;
    float a0 = 0.f, a1 = 0.f, a2 = 0.f, a3 = 0.f, a4 = 0.f, a5 = 0.f, a6 = 0.f, a7 = 0.f;
    for (int i = 0; i < cnt; i++) {
        uvec4 hn = (uvec4)(0u);
        if (i + 2 < cnt) {
            int sn = cp[i + 2];
            hn = *(const uvec4*)(hbuf + (size_t)sn * 32 + cb);
        }
        float v0 = bflo(h0.x), v1 = bfhi(h0.x), v2 = bflo(h0.y), v3 = bfhi(h0.y);
        float v4 = bflo(h0.z), v5 = bfhi(h0.z), v6 = bflo(h0.w), v7 = bfhi(h0.w);
        float as = v0 * A0 + v1 * A1 + v2 * A2 + v3 * A3
                 + v4 * A4 + v5 * A5 + v6 * A6 + v7 * A7;
        float e = as + adv;
        e = e > 0.f ? e : 0.2f * e;
        e = fminf(50.f, fmaxf(-50.f, e));
        float w = __expf(e);
        den += w;
        a0 = fmaf(w, v0, a0); a1 = fmaf(w, v1, a1);
        a2 = fmaf(w, v2, a2); a3 = fmaf(w, v3, a3);
        a4 = fmaf(w, v4, a4); a5 = fmaf(w, v5, a5);
        a6 = fmaf(w, v6, a6); a7 = fmaf(w, v7, a7);
        h0 = h1; h1 = hn;
    }
    float inv = 1.f / den;
    float o0 = lrelu(fmaf(a0, inv, bl[cb + 0]), 0.01f);
    float o1 = lrelu(fmaf(a1, inv, bl[cb + 1]), 0.01f);
    float o2 = lrelu(fmaf(a2, inv, bl[cb + 2]), 0.01f);
    float o3 = lrelu(fmaf(a3, inv, bl[cb + 3]), 0.01f);
    float o4 = lrelu(fmaf(a4, inv, bl[cb + 4]), 0.01f);
    float o5 = lrelu(fmaf(a5, inv, bl[cb + 5]), 0.01f);
    float o6 = lrelu(fmaf(a6, inv, bl[cb + 6]), 0.01f);
    float o7 = lrelu(fmaf(a7, inv, bl[cb + 7]), 0.01f);
    uvec4 p;
    p.x = ((unsigned int)f2bf_bits(o1) << 16) | f2bf_bits(o0);
    p.y = ((unsigned int)f2bf_bits(o3) << 16) | f2bf_bits(o2);
    p.z = ((unsigned int)f2bf_bits(o5) << 16) | f2bf_bits(o4);
    p.w = ((unsigned int)f2bf_bits(o7) << 16) | f2bf_bits(o6);
    __builtin_nontemporal_store(p, (uvec4*)(xxout + (size_t)n * 32 + cb));
}

// ---------------- layer 4: edge-parallel, one block per function node ----------------
__global__ void layer4_kernel(const bf16* __restrict__ xx,
                              const void* __restrict__ W4,
                              const void* __restrict__ asrc,
                              const void* __restrict__ adst,
                              const void* __restrict__ b4,
                              const int* __restrict__ fidx, const int* __restrict__ offs,
                              const int* __restrict__ csr, float* __restrict__ pool,
                              const void* __restrict__ x) {
    __shared__ float Wl[32 * 128];
    __shared__ float asl[128], adl[128], bl[32];
    __shared__ float accs[4][32];
    __shared__ float dens[4];
    __shared__ int fl;
    int tid = threadIdx.x;
    int f = flag_from_x(x, tid, &fl);
    for (int i = tid; i < 32 * 128; i += 256) Wl[i] = loadF(W4, i, f);
    if (tid < 128) { asl[tid] = loadF(asrc, tid, f); adl[tid] = loadF(adst, tid, f); accs[tid >> 5][tid & 31] = 0.f; }
    if (tid < 32) bl[tid] = loadF(b4, tid, f);
    if (tid < 4) dens[tid] = 0.f;
    __syncthreads();
    int g = blockIdx.x;
    int d = fidx[g];
    int wave = tid >> 6, lane = tid & 63;
    int c = lane & 31;
    int h0 = lane >> 5;
    int h1 = h0 + 2;
    const uvec4* xd4 = (const uvec4*)(xx + (size_t)d * 32);
    uvec4 du0 = xd4[0], du1 = xd4[1];
    float v0 = 0.f, v1 = 0.f;
    {
        unsigned int us[8] = {du0.x, du0.y, du0.z, du0.w, du1.x, du1.y, du1.z, du1.w};
#pragma unroll
        for (int q = 0; q < 8; q++) {
            unsigned int u = us[q];
            int k = 2 * q;
            v0 = fmaf(bflo(u), Wl[k * 128 + lane], v0);       v0 = fmaf(bfhi(u), Wl[(k + 1) * 128 + lane], v0);
            v1 = fmaf(bflo(u), Wl[k * 128 + lane + 64], v1);  v1 = fmaf(bfhi(u), Wl[(k + 1) * 128 + lane + 64], v1);
        }
    }
    float ad0 = v0 * adl[h0 * 32 + c];
    float ad1 = v1 * adl[h1 * 32 + c];
#pragma unroll
    for (int mk = 1; mk < 32; mk <<= 1) { ad0 += __shfl_xor(ad0, mk); ad1 += __shfl_xor(ad1, mk); }
    int beg = offs[d], end = offs[d + 1];
    float den0 = 0.f, den1 = 0.f, acc0 = 0.f, acc1 = 0.f;
    for (int i = beg + wave; i < end; i += 4) {
        int s = csr[i];
        const uvec4* xs4 = (const uvec4*)(xx + (size_t)s * 32);
        uvec4 su0 = xs4[0], su1 = xs4[1];
        float s0 = 0.f, s1 = 0.f;
        unsigned int us[8] = {su0.x, su0.y, su0.z, su0.w, su1.x, su1.y, su1.z, su1.w};
#pragma unroll
        for (int q = 0; q < 8; q++) {
            unsigned int u = us[q];
            int k = 2 * q;
            s0 = fmaf(bflo(u), Wl[k * 128 + lane], s0);       s0 = fmaf(bfhi(u), Wl[(k + 1) * 128 + lane], s0);
            s1 = fmaf(bflo(u), Wl[k * 128 + lane + 64], s1);  s1 = fmaf(bfhi(u), Wl[(k + 1) * 128 + lane + 64], s1);
        }
        float as0 = s0 * asl[h0 * 32 + c];
        float as1 = s1 * asl[h1 * 32 + c];
#pragma unroll
        for (int mk = 1; mk < 32; mk <<= 1) { as0 += __shfl_xor(as0, mk); as1 += __shfl_xor(as1, mk); }
        float e0 = lrelu(as0 + ad0, 0.2f);
        float e1 = lrelu(as1 + ad1, 0.2f);
        e0 = fminf(50.f, fmaxf(-50.f, e0));
        e1 = fminf(50.f, fmaxf(-50.f, e1));
        float w0 = __expf(e0), w1 = __expf(e1);
        den0 += w0; acc0 = fmaf(w0, s0, acc0);
        den1 += w1; acc1 = fmaf(w1, s1, acc1);
    }
    atomicAdd(&accs[h0][c], acc0);
    atomicAdd(&accs[h1][c], acc1);
    if (c == 0) { atomicAdd(&dens[h0], den0); atomicAdd(&dens[h1], den1); }
    __syncthreads();
    if (tid < 32) {
        float t = accs[0][tid] / dens[0] + accs[1][tid] / dens[1]
                + accs[2][tid] / dens[2] + accs[3][tid] / dens[3];
        float o = t * 0.25f + bl[tid];
        pool[g * 32 + tid] = lrelu(o, 0.01f);
    }
}

// ---------------- fused final scoring ----------------
__global__ void tail_kernel(const void* __restrict__ Wq, const void* __restrict__ Wk,
                            const void* __restrict__ Ws, const void* __restrict__ bs,
                            const int* __restrict__ gidx, const int* __restrict__ gsrc,
                            const float* __restrict__ pool, void* __restrict__ out,
                            const void* __restrict__ x) {
    __shared__ float vq[128], vk[128];
    __shared__ float sq[4096], sk[4096];
    __shared__ int fl;
    int tid = threadIdx.x;  // 256
    int f = flag_from_x(x, tid, &fl);
    {
        int which = tid >> 7;
        int i = tid & 127;
        int h = i >> 5, dd = i & 31;
        const void* Wm = which ? Wk : Wq;
        float sum = 0.f;
#pragma unroll
        for (int o = 0; o < 32; o++)
            sum = fmaf(loadF(Wm, (h * 32 + dd) * 32 + o, f), loadF(Ws, h * 64 + which * 32 + o, f), sum);
        (which ? vk : vq)[i] = sum;
    }
    __syncthreads();
    for (int idx = tid; idx < 8192; idx += 256) {
        int which = idx >> 12;
        int i = idx & 4095;
        int g = i >> 2, h = i & 3;
        const float* V = which ? vk : vq;
        float s = 0.f;
#pragma unroll
        for (int dd = 0; dd < 32; dd++) s = fmaf(pool[g * 32 + dd], V[h * 32 + dd], s);
        (which ? sk : sq)[i] = s;
    }
    __syncthreads();
    for (int t = tid; t < 4096; t += 256) {
        int g = t >> 2, h = t & 3;
        int i = gidx[g];
        float bsv = loadF(bs, h, f);
        float sqi = sq[i * 4 + h];
        float trg = sigm(sqi + sk[i * 4 + h] + bsv);
        float ga[3];
#pragma unroll
        for (int q = 0; q < 3; q++) {
            int jj = gsrc[g * 4 + 1 + q];
            ga[q] = sigm(sqi + sk[jj * 4 + h] + bsv);
        }
        float ss = (ga[0] + ga[1] + ga[2]) * (1.f / 3.f);
        float mx = fmaxf(ss, trg);
        float e0 = __expf(ss - mx), e1 = __expf(trg - mx);
        float inv = 1.f / (e0 + e1);
        float tw0 = e0 * inv, tw1 = e1 * inv;
        float mg = fmaxf(ga[0], fmaxf(ga[1], ga[2]));
        float w0 = __expf(ga[0] - mg), w1 = __expf(ga[1] - mg), w2 = __expf(ga[2] - mg);
        float wi = tw0 * 3.f / (w0 + w1 + w2);
        storeF(out, g * 16 + 0 + h,  tw1,     f);
        storeF(out, g * 16 + 4 + h,  w0 * wi, f);
        storeF(out, g * 16 + 8 + h,  w1 * wi, f);
        storeF(out, g * 16 + 12 + h, w2 * wi, f);
    }
}

extern "C" void kernel_launch(void* const* d_in, const int* in_sizes, int n_in,
                              void* d_out, int out_size, void* d_ws, size_t ws_size,
                              hipStream_t stream) {
    // -------- inputs --------
    const void* x        = d_in[0];
    const int*  ei       = (const int*)d_in[1];
    const void* a2s_msg  = d_in[2];
    const void* a2s_hid  = d_in[3];
    const void* s2a_msg  = d_in[4];
    const void* s2a_hid  = d_in[5];
    const void* prefix   = d_in[6];
    const int*  fidx     = (const int*)d_in[7];
    const int*  gidx     = (const int*)d_in[8];
    const int*  gsrc     = (const int*)d_in[9];
    const void* g1_Wih   = d_in[10];
    const void* g1_Whh   = d_in[11];
    const void* g1_bih   = d_in[12];
    const void* g1_bhh   = d_in[13];
    const void* g2_Wih   = d_in[14];
    const void* g2_Whh   = d_in[15];
    const void* g2_bih   = d_in[16];
    const void* g2_bhh   = d_in[17];
    const void* W1  = d_in[18];
    const void* as1 = d_in[19];
    const void* ad1 = d_in[20];
    const void* b1  = d_in[21];
    const void* W2  = d_in[22];
    const void* as2 = d_in[23];
    const void* ad2 = d_in[24];
    const void* b2  = d_in[25];
    const void* W3  = d_in[26];
    const void* as3 = d_in[27];
    const void* ad3 = d_in[28];
    const void* b3  = d_in[29];
    const void* W4  = d_in[30];
    const void* as4 = d_in[31];
    const void* ad4 = d_in[32];
    const void* b4  = d_in[33];
    const void* Wq  = d_in[34];
    const void* Wk  = d_in[35];
    const void* Ws  = d_in[36];
    const void* bs  = d_in[37];

    const int* src_e = ei;
    const int* dst_e = ei + EED;

    // -------- workspace layout (~50 MB of 256 MB) --------
    char* wp = (char*)d_ws;
    auto alloc = [&](size_t bytes) {
        char* p = wp;
        wp += (bytes + 255) & ~(size_t)255;
        return p;
    };
    int*   csr   = (int*)alloc((size_t)ETOT * 4);              // 8.8 MB
    int*   offs  = (int*)alloc((size_t)(NND + 1) * 4);         // 0.8 MB
    int*   gtail = (int*)alloc((size_t)NB * 4);
    float* pool  = (float*)alloc((size_t)MMD * 32 * 4);
    bf16*  bufA  = (bf16*)alloc((size_t)NND * 32 * 2);         // 12.8 MB
    bf16*  bufB  = (bf16*)alloc((size_t)NND * 32 * 2);         // 12.8 MB
    unsigned int* stage = (unsigned int*)alloc((size_t)NB * CAP * 4);  // 12.25 MB, DEDICATED

    // -------- CSR bin, then assemble+GRUs --------
    hipMemsetAsync(gtail, 0, (size_t)NB * 4, stream);
    bin_kernel<<<(ETOT + TILE - 1) / TILE, 256, 0, stream>>>(src_e, dst_e, gtail, stage);
    asmgru_kernel<<<ASM_BLK + GRU_BLK, 256, 0, stream>>>(
        x, prefix,
        a2s_msg, a2s_hid, g1_Wih, g1_Whh, g1_bih, g1_bhh,
        s2a_msg, s2a_hid, g2_Wih, g2_Whh, g2_bih, g2_bhh,
        d_out, bufA);

    // -------- mid: build + feat1 --------
    mid_kernel<<<NB + FEAT_BLK, 256, 0, stream>>>(stage, gtail, offs, csr, bufA, W1, bufB, x);

    // -------- GAT layers --------
    const int nblk_agg = NND / 64;  // 3125
    agg_kernel<<<nblk_agg, 256, 0, stream>>>(bufB, offs, csr, as1, ad1, b1, bufA, x);
    feat_kernel<32><<<FEAT_BLK, 256, 0, stream>>>(bufA, W2, bufB, x);
    agg_kernel<<<nblk_agg, 256, 0, stream>>>(bufB, offs, csr, as2, ad2, b2, bufA, x);
    feat_kernel<32><<<FEAT_BLK, 256, 0, stream>>>(bufA, W3, bufB, x);
    agg_kernel<<<nblk_agg, 256, 0, stream>>>(bufB, offs, csr, as3, ad3, b3, bufA, x);

    // -------- layer 4 + tail --------
    layer4_kernel<<<MMD, 256, 0, stream>>>(bufA, W4, as4, ad4, b4, fidx, offs, csr, pool, x);
    tail_kernel<<<1, 256, 0, stream>>>(Wq, Wk, Ws, bs, gidx, gsrc, pool, d_out, x);
}